// Round 1
// baseline (904.117 us; speedup 1.0000x reference)
//
#include <hip/hip_runtime.h>
#include <hip/hip_bf16.h>

typedef __bf16 bf16x8 __attribute__((ext_vector_type(8)));
typedef __bf16 bf16x4 __attribute__((ext_vector_type(4)));
typedef float f32x4 __attribute__((ext_vector_type(4)));

// ---------------- f32 -> bf16 conversion (4 elems/thread) ----------------
__global__ __launch_bounds__(256) void cvt_bf16(const float* __restrict__ in,
                                                __bf16* __restrict__ out, int n4) {
  int i = blockIdx.x * 256 + threadIdx.x;
  if (i >= n4) return;
  float4 v = ((const float4*)in)[i];
  bf16x4 o;
  o.x = (__bf16)v.x; o.y = (__bf16)v.y; o.z = (__bf16)v.z; o.w = (__bf16)v.w;
  ((bf16x4*)out)[i] = o;
}

// ---------------- C[M,N] = A[M,K] * B[N,K]^T + bias, bf16 in, f32 acc ----
// 128x128 tile, BK=64, 4 waves (2x2 of 64x64), 16x16x32 bf16 MFMA.
template<bool STORE_BF16>
__global__ __launch_bounds__(256) void gemm_bt(const __bf16* __restrict__ A,
                                               const __bf16* __restrict__ Bw,
                                               const float* __restrict__ bias,
                                               void* __restrict__ Cp,
                                               int M, int N, int K) {
  __shared__ __align__(16) __bf16 sA[128 * 64];
  __shared__ __align__(16) __bf16 sB[128 * 64];
  const int tid = threadIdx.x;
  const int lane = tid & 63;
  const int w = tid >> 6;
  const int wr = w >> 1, wc = w & 1;
  const int l15 = lane & 15, q4 = lane >> 4;
  const int bm = blockIdx.x, bn = blockIdx.y;

  f32x4 acc[4][4] = {};

  for (int k0 = 0; k0 < K; k0 += 64) {
    __syncthreads();
#pragma unroll
    for (int it = 0; it < 4; ++it) {
      int chunk = it * 256 + tid;              // 1024 16B chunks per tile
      int row = chunk >> 3, c8 = chunk & 7;
      *(uint4*)(sA + chunk * 8) =
          *(const uint4*)(A + (size_t)(bm * 128 + row) * K + k0 + c8 * 8);
      *(uint4*)(sB + chunk * 8) =
          *(const uint4*)(Bw + (size_t)(bn * 128 + row) * K + k0 + c8 * 8);
    }
    __syncthreads();
#pragma unroll
    for (int kk = 0; kk < 2; ++kk) {
      bf16x8 af[4], bfr[4];
#pragma unroll
      for (int i = 0; i < 4; ++i)
        af[i] = *(const bf16x8*)(sA + (wr * 64 + i * 16 + l15) * 64 + kk * 32 + q4 * 8);
#pragma unroll
      for (int j = 0; j < 4; ++j)
        bfr[j] = *(const bf16x8*)(sB + (wc * 64 + j * 16 + l15) * 64 + kk * 32 + q4 * 8);
#pragma unroll
      for (int i = 0; i < 4; ++i)
#pragma unroll
        for (int j = 0; j < 4; ++j)
          acc[i][j] = __builtin_amdgcn_mfma_f32_16x16x32_bf16(af[i], bfr[j], acc[i][j], 0, 0, 0);
    }
  }
#pragma unroll
  for (int j = 0; j < 4; ++j) {
    const int col = bn * 128 + wc * 64 + j * 16 + l15;
    const float bv = bias[col];
#pragma unroll
    for (int i = 0; i < 4; ++i) {
      const int row0 = bm * 128 + wr * 64 + i * 16 + q4 * 4;
#pragma unroll
      for (int r = 0; r < 4; ++r) {
        float v = acc[i][j][r] + bv;
        size_t off = (size_t)(row0 + r) * N + col;
        if (STORE_BF16) ((__bf16*)Cp)[off] = (__bf16)v;
        else            ((float*)Cp)[off]  = v;
      }
    }
  }
}

// ---------------- kv epilogue: LN(k) -> K (b,nh,s2,d); v -> V^T (b,nh,d,s2)
__global__ __launch_bounds__(256) void kv_epilogue(const float* __restrict__ kv,
                                                   const float* __restrict__ g,
                                                   const float* __restrict__ bta,
                                                   __bf16* __restrict__ Kd,
                                                   __bf16* __restrict__ VT) {
  const int lane = threadIdx.x & 63;
  const int vec = blockIdx.x * 4 + (threadIdx.x >> 6);  // 2048 rows * {k,v} * 16 heads
  const int nh = vec & 15;
  const int sv = (vec >> 4) & 1;
  const int row = vec >> 5;            // b*256 + s2
  const int b = row >> 8, s2 = row & 255;
  float v = kv[(size_t)row * 2048 + sv * 1024 + nh * 64 + lane];
  if (sv == 0) {
    float mu = v;
#pragma unroll
    for (int o = 32; o; o >>= 1) mu += __shfl_xor(mu, o);
    mu *= (1.f / 64.f);
    float d = v - mu;
    float va = d * d;
#pragma unroll
    for (int o = 32; o; o >>= 1) va += __shfl_xor(va, o);
    va *= (1.f / 64.f);
    float xn = d * rsqrtf(va + 1e-6f) * g[lane] + bta[lane];
    Kd[(((size_t)b * 16 + nh) * 256 + s2) * 64 + lane] = (__bf16)xn;
  } else {
    VT[(((size_t)b * 16 + nh) * 64 + lane) * 256 + s2] = (__bf16)v;
  }
}

// ---------------- q epilogue: LN + 2D-RoPE + *SCALE -> Q (b,nh,s1,d) ------
__global__ __launch_bounds__(256) void q_epilogue(const __bf16* __restrict__ qraw,
                                                  const float* __restrict__ g,
                                                  const float* __restrict__ bta,
                                                  __bf16* __restrict__ Q) {
  const int lane = threadIdx.x & 63;
  const int vec = blockIdx.x * 4 + (threadIdx.x >> 6);  // 32768 rows * 16 heads
  const int nh = vec & 15;
  const int row = vec >> 4;            // b*4096 + s1
  float v = (float)qraw[(size_t)row * 1024 + nh * 64 + lane];
  float mu = v;
#pragma unroll
  for (int o = 32; o; o >>= 1) mu += __shfl_xor(mu, o);
  mu *= (1.f / 64.f);
  float d = v - mu;
  float va = d * d;
#pragma unroll
  for (int o = 32; o; o >>= 1) va += __shfl_xor(va, o);
  va *= (1.f / 64.f);
  float xn = d * rsqrtf(va + 1e-6f) * g[lane] + bta[lane];
  // 2D RoPE: lane d -> pair p=d>>1, t=d>>2, (p&1) selects w-axis, else h-axis
  const int s1 = row & 4095;
  const int hh = s1 >> 6, wpix = s1 & 63;
  const int t = lane >> 2;
  const int usew = (lane >> 1) & 1;
  float inv = powf(10000.f, -(float)t * (1.f / 16.f));
  float ang = (usew ? (float)wpix : (float)hh) * inv;
  float cc = cosf(ang), ssn = sinf(ang);
  float partner = __shfl_xor(xn, 1);
  float rot = xn * cc + partner * ssn * ((lane & 1) ? 1.f : -1.f);
  rot *= 0.125f;  // SCALE folded into Q
  const int b = row >> 12;
  Q[(((size_t)b * 16 + nh) * 4096 + (size_t)s1) * 64 + lane] = (__bf16)rot;
}

// ---------------- fused attention: per (b,nh, 64-row q tile) --------------
// S = Q*K^T (MFMA), full-row softmax, P -> LDS (A-layout), O = P*V (MFMA).
__global__ __launch_bounds__(256) void attn_kernel(const __bf16* __restrict__ Q,
                                                   const __bf16* __restrict__ Kd,
                                                   const __bf16* __restrict__ VT,
                                                   __bf16* __restrict__ O) {
  __shared__ __align__(16) __bf16 sK[256 * 64];   // K tile (32KB); reused as P (64x256)
  const int tid = threadIdx.x, lane = tid & 63, w = tid >> 6;
  const int l15 = lane & 15, q4 = lane >> 4;
  const int bh = blockIdx.y;            // b*16 + nh
  const int m0 = blockIdx.x * 64;       // q-row tile base
  const __bf16* Kg = Kd + (size_t)bh * 256 * 64;
  const __bf16* Vg = VT + (size_t)bh * 64 * 256;
  const __bf16* Qg = Q + ((size_t)bh * 4096 + m0) * 64;
#pragma unroll
  for (int it = 0; it < 8; ++it) {
    int c = it * 256 + tid;
    *(uint4*)(sK + c * 8) = *(const uint4*)(Kg + c * 8);
  }
  __syncthreads();
  // S: wave w owns rows [w*16, w*16+16), all 256 cols -> 16 N-frags
  f32x4 sacc[16] = {};
#pragma unroll
  for (int kk = 0; kk < 2; ++kk) {
    bf16x8 a = *(const bf16x8*)(Qg + (w * 16 + l15) * 64 + kk * 32 + q4 * 8);
#pragma unroll
    for (int f = 0; f < 16; ++f) {
      bf16x8 b = *(const bf16x8*)(sK + (f * 16 + l15) * 64 + kk * 32 + q4 * 8);
      sacc[f] = __builtin_amdgcn_mfma_f32_16x16x32_bf16(a, b, sacc[f], 0, 0, 0);
    }
  }
  __syncthreads();  // all waves done reading K before P overwrites sK
  float linv[4];
#pragma unroll
  for (int r = 0; r < 4; ++r) {
    float m = -1e30f;
#pragma unroll
    for (int f = 0; f < 16; ++f) m = fmaxf(m, sacc[f][r]);
#pragma unroll
    for (int o = 1; o < 16; o <<= 1) m = fmaxf(m, __shfl_xor(m, o));
    float l = 0.f;
#pragma unroll
    for (int f = 0; f < 16; ++f) {
      float p = __expf(sacc[f][r] - m);
      sacc[f][r] = p;
      l += p;
    }
#pragma unroll
    for (int o = 1; o < 16; o <<= 1) l += __shfl_xor(l, o);
    linv[r] = 1.f / l;
    // P row (w*16 + q4*4 + r), row-major stride 256 -> A-operand friendly
    __bf16* prow = sK + (w * 16 + q4 * 4 + r) * 256;
#pragma unroll
    for (int f = 0; f < 16; ++f) prow[f * 16 + l15] = (__bf16)sacc[f][r];
  }
  // PV: wave reads only its own P rows (no barrier needed); V frags from global
  f32x4 oacc[4] = {};
#pragma unroll
  for (int ks = 0; ks < 8; ++ks) {
    bf16x8 a = *(const bf16x8*)(sK + (w * 16 + l15) * 256 + ks * 32 + q4 * 8);
#pragma unroll
    for (int j = 0; j < 4; ++j) {
      bf16x8 b = *(const bf16x8*)(Vg + (j * 16 + l15) * 256 + ks * 32 + q4 * 8);
      oacc[j] = __builtin_amdgcn_mfma_f32_16x16x32_bf16(a, b, oacc[j], 0, 0, 0);
    }
  }
  const int b = bh >> 4, nh = bh & 15;
#pragma unroll
  for (int j = 0; j < 4; ++j)
#pragma unroll
    for (int r = 0; r < 4; ++r) {
      size_t off = ((size_t)b * 4096 + m0 + w * 16 + q4 * 4 + r) * 1024
                 + nh * 64 + j * 16 + l15;
      O[off] = (__bf16)(oacc[j][r] * linv[r]);
    }
}

extern "C" void kernel_launch(void* const* d_in, const int* in_sizes, int n_in,
                              void* d_out, int out_size, void* d_ws, size_t ws_size,
                              hipStream_t stream) {
  const float* x    = (const float*)d_in[0];
  const float* y    = (const float*)d_in[1];
  const float* wq   = (const float*)d_in[2];
  const float* bq   = (const float*)d_in[3];
  const float* wkv  = (const float*)d_in[4];
  const float* bkv  = (const float*)d_in[5];
  const float* wo   = (const float*)d_in[6];
  const float* bo   = (const float*)d_in[7];
  const float* qng  = (const float*)d_in[8];
  const float* qnb  = (const float*)d_in[9];
  const float* kng  = (const float*)d_in[10];
  const float* knb  = (const float*)d_in[11];
  float* out = (float*)d_out;

  char* ws = (char*)d_ws;
  size_t off = 0;
  auto take = [&](size_t bytes) { char* p = ws + off; off += (bytes + 255) & ~(size_t)255; return p; };
  __bf16* xb   = (__bf16*)take((size_t)32768 * 1024 * 2);  // x bf16; later aliased as attn_out
  char*  reg1  = take((size_t)32768 * 1024 * 2);           // kv_f32 (head 16.8MB), then q_raw
  __bf16* Qb   = (__bf16*)take((size_t)32768 * 1024 * 2);  // final Q (b,nh,s1,d)
  __bf16* yb   = (__bf16*)take((size_t)2048 * 2048 * 2);
  __bf16* wqb  = (__bf16*)take((size_t)1024 * 1024 * 2);
  __bf16* wkvb = (__bf16*)take((size_t)2048 * 2048 * 2);
  __bf16* wob  = (__bf16*)take((size_t)1024 * 1024 * 2);
  __bf16* Kb   = (__bf16*)take((size_t)128 * 256 * 64 * 2);
  __bf16* VTb  = (__bf16*)take((size_t)128 * 64 * 256 * 2);
  float*  kvf  = (float*)reg1;    // live: kv GEMM -> kv_epilogue
  __bf16* qraw = (__bf16*)reg1;   // live: q GEMM -> q_epilogue (after kvf dead)
  __bf16* aout = xb;              // live: attn -> out GEMM (after xb dead)

  // f32 -> bf16 conversions
  cvt_bf16<<<32768, 256, 0, stream>>>(x,   xb,   8388608);
  cvt_bf16<<<4096,  256, 0, stream>>>(y,   yb,   1048576);
  cvt_bf16<<<1024,  256, 0, stream>>>(wq,  wqb,  262144);
  cvt_bf16<<<4096,  256, 0, stream>>>(wkv, wkvb, 1048576);
  cvt_bf16<<<1024,  256, 0, stream>>>(wo,  wob,  262144);

  // kv = y @ wkv^T + bkv  (f32 out), then LN(k)->K, v->V^T
  gemm_bt<false><<<dim3(16, 16), 256, 0, stream>>>(yb, wkvb, bkv, kvf, 2048, 2048, 2048);
  kv_epilogue<<<16384, 256, 0, stream>>>(kvf, kng, knb, Kb, VTb);

  // q_raw = x @ wq^T + bq (bf16 out), then LN + RoPE + scale -> Q
  gemm_bt<true><<<dim3(256, 8), 256, 0, stream>>>(xb, wqb, bq, qraw, 32768, 1024, 1024);
  q_epilogue<<<131072, 256, 0, stream>>>(qraw, qng, qnb, Qb);

  // fused attention -> aout (b,s1,nh*hd) bf16
  attn_kernel<<<dim3(64, 128), 256, 0, stream>>>(Qb, Kb, VTb, aout);

  // out = aout @ wo^T + bo (f32 out)
  gemm_bt<false><<<dim3(256, 8), 256, 0, stream>>>(aout, wob, bo, out, 32768, 1024, 1024);
}

// Round 2
// 797.767 us; speedup vs baseline: 1.1333x; 1.1333x over previous
//
#include <hip/hip_runtime.h>
#include <hip/hip_bf16.h>

typedef __bf16 bf16x8 __attribute__((ext_vector_type(8)));
typedef __bf16 bf16x4 __attribute__((ext_vector_type(4)));
typedef float f32x4 __attribute__((ext_vector_type(4)));

// Direct global->LDS async copy, 16B per lane. LDS dest must be the
// wave-uniform base; HW places lane i at base + i*16B.
__device__ __forceinline__ void async_copy16(__bf16* lds_base, const __bf16* g) {
  __builtin_amdgcn_global_load_lds(
      (const __attribute__((address_space(1))) void*)g,
      (__attribute__((address_space(3))) void*)lds_base, 16, 0, 0);
}

// ---------------- f32 -> bf16 conversion (4 elems/thread) ----------------
__global__ __launch_bounds__(256) void cvt_bf16(const float* __restrict__ in,
                                                __bf16* __restrict__ out, int n4) {
  int i = blockIdx.x * 256 + threadIdx.x;
  if (i >= n4) return;
  float4 v = ((const float4*)in)[i];
  bf16x4 o;
  o.x = (__bf16)v.x; o.y = (__bf16)v.y; o.z = (__bf16)v.z; o.w = (__bf16)v.w;
  ((bf16x4*)out)[i] = o;
}

// ---------------- C[M,N] = A[M,K] * B[N,K]^T + bias, bf16 in, f32 acc ----
// 128x128 tile, BK=64, 4 waves (2x2 of 64x64), 16x16x32 bf16 MFMA.
// Staging via global_load_lds width=16 (m97 pattern).
template<bool STORE_BF16>
__global__ __launch_bounds__(256) void gemm_bt(const __bf16* __restrict__ A,
                                               const __bf16* __restrict__ Bw,
                                               const float* __restrict__ bias,
                                               void* __restrict__ Cp,
                                               int M, int N, int K) {
  __shared__ __align__(16) __bf16 sA[128 * 64];
  __shared__ __align__(16) __bf16 sB[128 * 64];
  const int tid = threadIdx.x;
  const int lane = tid & 63;
  const int w = tid >> 6;
  const int wr = w >> 1, wc = w & 1;
  const int l15 = lane & 15, q4 = lane >> 4;
  const int bm = blockIdx.x, bn = blockIdx.y;

  f32x4 acc[4][4] = {};

  for (int k0 = 0; k0 < K; k0 += 64) {
    __syncthreads();  // previous iter's LDS reads done
#pragma unroll
    for (int it = 0; it < 4; ++it) {
      int chunk = it * 256 + tid;              // 1024 16B chunks per tile
      int row = chunk >> 3, c8 = chunk & 7;
      int ldsbase = (it * 256 + w * 64) * 8;   // wave-uniform; lane lands at +lane*8
      async_copy16(sA + ldsbase, A + (size_t)(bm * 128 + row) * K + k0 + c8 * 8);
      async_copy16(sB + ldsbase, Bw + (size_t)(bn * 128 + row) * K + k0 + c8 * 8);
    }
    __syncthreads();  // vmcnt(0) drain + barrier: LDS tiles ready
#pragma unroll
    for (int kk = 0; kk < 2; ++kk) {
      bf16x8 af[4], bfr[4];
#pragma unroll
      for (int i = 0; i < 4; ++i)
        af[i] = *(const bf16x8*)(sA + (wr * 64 + i * 16 + l15) * 64 + kk * 32 + q4 * 8);
#pragma unroll
      for (int j = 0; j < 4; ++j)
        bfr[j] = *(const bf16x8*)(sB + (wc * 64 + j * 16 + l15) * 64 + kk * 32 + q4 * 8);
#pragma unroll
      for (int i = 0; i < 4; ++i)
#pragma unroll
        for (int j = 0; j < 4; ++j)
          acc[i][j] = __builtin_amdgcn_mfma_f32_16x16x32_bf16(af[i], bfr[j], acc[i][j], 0, 0, 0);
    }
  }
#pragma unroll
  for (int j = 0; j < 4; ++j) {
    const int col = bn * 128 + wc * 64 + j * 16 + l15;
    const float bv = bias[col];
#pragma unroll
    for (int i = 0; i < 4; ++i) {
      const int row0 = bm * 128 + wr * 64 + i * 16 + q4 * 4;
#pragma unroll
      for (int r = 0; r < 4; ++r) {
        float v = acc[i][j][r] + bv;
        size_t off = (size_t)(row0 + r) * N + col;
        if (STORE_BF16) ((__bf16*)Cp)[off] = (__bf16)v;
        else            ((float*)Cp)[off]  = v;
      }
    }
  }
}

// ---------------- kv epilogue: LN(k) -> K (b,nh,s2,d); v -> V^T (b,nh,d,s2)
__global__ __launch_bounds__(256) void kv_epilogue(const float* __restrict__ kv,
                                                   const float* __restrict__ g,
                                                   const float* __restrict__ bta,
                                                   __bf16* __restrict__ Kd,
                                                   __bf16* __restrict__ VT) {
  const int lane = threadIdx.x & 63;
  const int vec = blockIdx.x * 4 + (threadIdx.x >> 6);  // 2048 rows * {k,v} * 16 heads
  const int nh = vec & 15;
  const int sv = (vec >> 4) & 1;
  const int row = vec >> 5;            // b*256 + s2
  const int b = row >> 8, s2 = row & 255;
  float v = kv[(size_t)row * 2048 + sv * 1024 + nh * 64 + lane];
  if (sv == 0) {
    float mu = v;
#pragma unroll
    for (int o = 32; o; o >>= 1) mu += __shfl_xor(mu, o);
    mu *= (1.f / 64.f);
    float d = v - mu;
    float va = d * d;
#pragma unroll
    for (int o = 32; o; o >>= 1) va += __shfl_xor(va, o);
    va *= (1.f / 64.f);
    float xn = d * rsqrtf(va + 1e-6f) * g[lane] + bta[lane];
    Kd[(((size_t)b * 16 + nh) * 256 + s2) * 64 + lane] = (__bf16)xn;
  } else {
    VT[(((size_t)b * 16 + nh) * 64 + lane) * 256 + s2] = (__bf16)v;
  }
}

// ---------------- q epilogue: LN + 2D-RoPE + *SCALE -> Q (b,nh,s1,d) ------
__global__ __launch_bounds__(256) void q_epilogue(const __bf16* __restrict__ qraw,
                                                  const float* __restrict__ g,
                                                  const float* __restrict__ bta,
                                                  __bf16* __restrict__ Q) {
  const int lane = threadIdx.x & 63;
  const int vec = blockIdx.x * 4 + (threadIdx.x >> 6);  // 32768 rows * 16 heads
  const int nh = vec & 15;
  const int row = vec >> 4;            // b*4096 + s1
  float v = (float)qraw[(size_t)row * 1024 + nh * 64 + lane];
  float mu = v;
#pragma unroll
  for (int o = 32; o; o >>= 1) mu += __shfl_xor(mu, o);
  mu *= (1.f / 64.f);
  float d = v - mu;
  float va = d * d;
#pragma unroll
  for (int o = 32; o; o >>= 1) va += __shfl_xor(va, o);
  va *= (1.f / 64.f);
  float xn = d * rsqrtf(va + 1e-6f) * g[lane] + bta[lane];
  // 2D RoPE: lane d -> pair p=d>>1, t=d>>2, (p&1) selects w-axis, else h-axis
  const int s1 = row & 4095;
  const int hh = s1 >> 6, wpix = s1 & 63;
  const int t = lane >> 2;
  const int usew = (lane >> 1) & 1;
  // inv = 10000^(-t/16) = exp(-t * ln(10000)/16); hw v_exp path
  float inv = __expf(-(float)t * 0.5756462732485114f);
  float ang = (usew ? (float)wpix : (float)hh) * inv;
  float cc = __cosf(ang), ssn = __sinf(ang);   // hw v_cos/v_sin
  float partner = __shfl_xor(xn, 1);
  float rot = xn * cc + partner * ssn * ((lane & 1) ? 1.f : -1.f);
  rot *= 0.125f;  // SCALE folded into Q
  const int b = row >> 12;
  Q[(((size_t)b * 16 + nh) * 4096 + (size_t)s1) * 64 + lane] = (__bf16)rot;
}

// ---------------- fused attention: per (b,nh, 64-row q tile) --------------
// S = Q*K^T (MFMA), full-row softmax, P -> LDS (A-layout), O = P*V (MFMA).
__global__ __launch_bounds__(256) void attn_kernel(const __bf16* __restrict__ Q,
                                                   const __bf16* __restrict__ Kd,
                                                   const __bf16* __restrict__ VT,
                                                   __bf16* __restrict__ O) {
  __shared__ __align__(16) __bf16 sK[256 * 64];   // K tile (32KB); reused as P (64x256)
  const int tid = threadIdx.x, lane = tid & 63, w = tid >> 6;
  const int l15 = lane & 15, q4 = lane >> 4;
  const int bh = blockIdx.y;            // b*16 + nh
  const int m0 = blockIdx.x * 64;       // q-row tile base
  const __bf16* Kg = Kd + (size_t)bh * 256 * 64;
  const __bf16* Vg = VT + (size_t)bh * 64 * 256;
  const __bf16* Qg = Q + ((size_t)bh * 4096 + m0) * 64;
#pragma unroll
  for (int it = 0; it < 8; ++it) {
    int c = it * 256 + tid;
    *(uint4*)(sK + c * 8) = *(const uint4*)(Kg + c * 8);
  }
  __syncthreads();
  // S: wave w owns rows [w*16, w*16+16), all 256 cols -> 16 N-frags
  f32x4 sacc[16] = {};
#pragma unroll
  for (int kk = 0; kk < 2; ++kk) {
    bf16x8 a = *(const bf16x8*)(Qg + (w * 16 + l15) * 64 + kk * 32 + q4 * 8);
#pragma unroll
    for (int f = 0; f < 16; ++f) {
      bf16x8 b = *(const bf16x8*)(sK + (f * 16 + l15) * 64 + kk * 32 + q4 * 8);
      sacc[f] = __builtin_amdgcn_mfma_f32_16x16x32_bf16(a, b, sacc[f], 0, 0, 0);
    }
  }
  __syncthreads();  // all waves done reading K before P overwrites sK
  float linv[4];
#pragma unroll
  for (int r = 0; r < 4; ++r) {
    float m = -1e30f;
#pragma unroll
    for (int f = 0; f < 16; ++f) m = fmaxf(m, sacc[f][r]);
#pragma unroll
    for (int o = 1; o < 16; o <<= 1) m = fmaxf(m, __shfl_xor(m, o));
    float l = 0.f;
#pragma unroll
    for (int f = 0; f < 16; ++f) {
      float p = __expf(sacc[f][r] - m);
      sacc[f][r] = p;
      l += p;
    }
#pragma unroll
    for (int o = 1; o < 16; o <<= 1) l += __shfl_xor(l, o);
    linv[r] = 1.f / l;
    // P row (w*16 + q4*4 + r), row-major stride 256 -> A-operand friendly
    __bf16* prow = sK + (w * 16 + q4 * 4 + r) * 256;
#pragma unroll
    for (int f = 0; f < 16; ++f) prow[f * 16 + l15] = (__bf16)sacc[f][r];
  }
  // PV: wave reads only its own P rows (no barrier needed); V frags from global
  f32x4 oacc[4] = {};
#pragma unroll
  for (int ks = 0; ks < 8; ++ks) {
    bf16x8 a = *(const bf16x8*)(sK + (w * 16 + l15) * 256 + ks * 32 + q4 * 8);
#pragma unroll
    for (int j = 0; j < 4; ++j) {
      bf16x8 b = *(const bf16x8*)(Vg + (j * 16 + l15) * 256 + ks * 32 + q4 * 8);
      oacc[j] = __builtin_amdgcn_mfma_f32_16x16x32_bf16(a, b, oacc[j], 0, 0, 0);
    }
  }
  const int b = bh >> 4, nh = bh & 15;
#pragma unroll
  for (int j = 0; j < 4; ++j)
#pragma unroll
    for (int r = 0; r < 4; ++r) {
      size_t off = ((size_t)b * 4096 + m0 + w * 16 + q4 * 4 + r) * 1024
                 + nh * 64 + j * 16 + l15;
      O[off] = (__bf16)(oacc[j][r] * linv[r]);
    }
}

extern "C" void kernel_launch(void* const* d_in, const int* in_sizes, int n_in,
                              void* d_out, int out_size, void* d_ws, size_t ws_size,
                              hipStream_t stream) {
  const float* x    = (const float*)d_in[0];
  const float* y    = (const float*)d_in[1];
  const float* wq   = (const float*)d_in[2];
  const float* bq   = (const float*)d_in[3];
  const float* wkv  = (const float*)d_in[4];
  const float* bkv  = (const float*)d_in[5];
  const float* wo   = (const float*)d_in[6];
  const float* bo   = (const float*)d_in[7];
  const float* qng  = (const float*)d_in[8];
  const float* qnb  = (const float*)d_in[9];
  const float* kng  = (const float*)d_in[10];
  const float* knb  = (const float*)d_in[11];
  float* out = (float*)d_out;

  char* ws = (char*)d_ws;
  size_t off = 0;
  auto take = [&](size_t bytes) { char* p = ws + off; off += (bytes + 255) & ~(size_t)255; return p; };
  __bf16* xb   = (__bf16*)take((size_t)32768 * 1024 * 2);  // x bf16; later aliased as attn_out
  char*  reg1  = take((size_t)32768 * 1024 * 2);           // kv_f32 (head 16.8MB), then q_raw
  __bf16* Qb   = (__bf16*)take((size_t)32768 * 1024 * 2);  // final Q (b,nh,s1,d)
  __bf16* yb   = (__bf16*)take((size_t)2048 * 2048 * 2);
  __bf16* wqb  = (__bf16*)take((size_t)1024 * 1024 * 2);
  __bf16* wkvb = (__bf16*)take((size_t)2048 * 2048 * 2);
  __bf16* wob  = (__bf16*)take((size_t)1024 * 1024 * 2);
  __bf16* Kb   = (__bf16*)take((size_t)128 * 256 * 64 * 2);
  __bf16* VTb  = (__bf16*)take((size_t)128 * 64 * 256 * 2);
  float*  kvf  = (float*)reg1;    // live: kv GEMM -> kv_epilogue
  __bf16* qraw = (__bf16*)reg1;   // live: q GEMM -> q_epilogue (after kvf dead)
  __bf16* aout = xb;              // live: attn -> out GEMM (after xb dead)

  // f32 -> bf16 conversions
  cvt_bf16<<<32768, 256, 0, stream>>>(x,   xb,   8388608);
  cvt_bf16<<<4096,  256, 0, stream>>>(y,   yb,   1048576);
  cvt_bf16<<<1024,  256, 0, stream>>>(wq,  wqb,  262144);
  cvt_bf16<<<4096,  256, 0, stream>>>(wkv, wkvb, 1048576);
  cvt_bf16<<<1024,  256, 0, stream>>>(wo,  wob,  262144);

  // kv = y @ wkv^T + bkv  (f32 out), then LN(k)->K, v->V^T
  gemm_bt<false><<<dim3(16, 16), 256, 0, stream>>>(yb, wkvb, bkv, kvf, 2048, 2048, 2048);
  kv_epilogue<<<16384, 256, 0, stream>>>(kvf, kng, knb, Kb, VTb);

  // q_raw = x @ wq^T + bq (bf16 out), then LN + RoPE + scale -> Q
  gemm_bt<true><<<dim3(256, 8), 256, 0, stream>>>(xb, wqb, bq, qraw, 32768, 1024, 1024);
  q_epilogue<<<131072, 256, 0, stream>>>(qraw, qng, qnb, Qb);

  // fused attention -> aout (b,s1,nh*hd) bf16
  attn_kernel<<<dim3(64, 128), 256, 0, stream>>>(Qb, Kb, VTb, aout);

  // out = aout @ wo^T + bo (f32 out)
  gemm_bt<false><<<dim3(256, 8), 256, 0, stream>>>(aout, wob, bo, out, 32768, 1024, 1024);
}

// Round 3
// 718.834 us; speedup vs baseline: 1.2578x; 1.1098x over previous
//
#include <hip/hip_runtime.h>
#include <hip/hip_bf16.h>

typedef __bf16 bf16x8 __attribute__((ext_vector_type(8)));
typedef __bf16 bf16x4 __attribute__((ext_vector_type(4)));
typedef float f32x4 __attribute__((ext_vector_type(4)));

// Direct global->LDS async copy, 16B per lane. LDS dest must be the
// wave-uniform base; HW places lane i at base + i*16B.
__device__ __forceinline__ void async_copy16(__bf16* lds_base, const __bf16* g) {
  __builtin_amdgcn_global_load_lds(
      (const __attribute__((address_space(1))) void*)g,
      (__attribute__((address_space(3))) void*)lds_base, 16, 0, 0);
}

// ---------------- f32 -> bf16 conversion (4 elems/thread) ----------------
__global__ __launch_bounds__(256) void cvt_bf16(const float* __restrict__ in,
                                                __bf16* __restrict__ out, int n4) {
  int i = blockIdx.x * 256 + threadIdx.x;
  if (i >= n4) return;
  float4 v = ((const float4*)in)[i];
  bf16x4 o;
  o.x = (__bf16)v.x; o.y = (__bf16)v.y; o.z = (__bf16)v.z; o.w = (__bf16)v.w;
  ((bf16x4*)out)[i] = o;
}

// ---------------- C[M,N] = A[M,K] * B[N,K]^T + bias, bf16 in, f32 acc ----
// 128x128 tile, BK=64, 4 waves (2x2 of 64x64), 16x16x32 bf16 MFMA.
// Staging via global_load_lds width=16 (m97 pattern).
template<bool STORE_BF16>
__global__ __launch_bounds__(256) void gemm_bt(const __bf16* __restrict__ A,
                                               const __bf16* __restrict__ Bw,
                                               const float* __restrict__ bias,
                                               void* __restrict__ Cp,
                                               int M, int N, int K) {
  __shared__ __align__(16) __bf16 sA[128 * 64];
  __shared__ __align__(16) __bf16 sB[128 * 64];
  const int tid = threadIdx.x;
  const int lane = tid & 63;
  const int w = tid >> 6;
  const int wr = w >> 1, wc = w & 1;
  const int l15 = lane & 15, q4 = lane >> 4;
  const int bm = blockIdx.x, bn = blockIdx.y;

  f32x4 acc[4][4] = {};

  for (int k0 = 0; k0 < K; k0 += 64) {
    __syncthreads();  // previous iter's LDS reads done
#pragma unroll
    for (int it = 0; it < 4; ++it) {
      int chunk = it * 256 + tid;              // 1024 16B chunks per tile
      int row = chunk >> 3, c8 = chunk & 7;
      int ldsbase = (it * 256 + w * 64) * 8;   // wave-uniform; lane lands at +lane*8
      async_copy16(sA + ldsbase, A + (size_t)(bm * 128 + row) * K + k0 + c8 * 8);
      async_copy16(sB + ldsbase, Bw + (size_t)(bn * 128 + row) * K + k0 + c8 * 8);
    }
    __syncthreads();  // vmcnt(0) drain + barrier: LDS tiles ready
#pragma unroll
    for (int kk = 0; kk < 2; ++kk) {
      bf16x8 af[4], bfr[4];
#pragma unroll
      for (int i = 0; i < 4; ++i)
        af[i] = *(const bf16x8*)(sA + (wr * 64 + i * 16 + l15) * 64 + kk * 32 + q4 * 8);
#pragma unroll
      for (int j = 0; j < 4; ++j)
        bfr[j] = *(const bf16x8*)(sB + (wc * 64 + j * 16 + l15) * 64 + kk * 32 + q4 * 8);
#pragma unroll
      for (int i = 0; i < 4; ++i)
#pragma unroll
        for (int j = 0; j < 4; ++j)
          acc[i][j] = __builtin_amdgcn_mfma_f32_16x16x32_bf16(af[i], bfr[j], acc[i][j], 0, 0, 0);
    }
  }
#pragma unroll
  for (int j = 0; j < 4; ++j) {
    const int col = bn * 128 + wc * 64 + j * 16 + l15;
    const float bv = bias[col];
#pragma unroll
    for (int i = 0; i < 4; ++i) {
      const int row0 = bm * 128 + wr * 64 + i * 16 + q4 * 4;
#pragma unroll
      for (int r = 0; r < 4; ++r) {
        float v = acc[i][j][r] + bv;
        size_t off = (size_t)(row0 + r) * N + col;
        if (STORE_BF16) ((__bf16*)Cp)[off] = (__bf16)v;
        else            ((float*)Cp)[off]  = v;
      }
    }
  }
}

// ---------------- kv epilogue: LN(k) -> K (b,nh,s2,d); v -> V^T (b,nh,d,s2)
__global__ __launch_bounds__(256) void kv_epilogue(const float* __restrict__ kv,
                                                   const float* __restrict__ g,
                                                   const float* __restrict__ bta,
                                                   __bf16* __restrict__ Kd,
                                                   __bf16* __restrict__ VT) {
  const int lane = threadIdx.x & 63;
  const int vec = blockIdx.x * 4 + (threadIdx.x >> 6);  // 2048 rows * {k,v} * 16 heads
  const int nh = vec & 15;
  const int sv = (vec >> 4) & 1;
  const int row = vec >> 5;            // b*256 + s2
  const int b = row >> 8, s2 = row & 255;
  float v = kv[(size_t)row * 2048 + sv * 1024 + nh * 64 + lane];
  if (sv == 0) {
    float mu = v;
#pragma unroll
    for (int o = 32; o; o >>= 1) mu += __shfl_xor(mu, o);
    mu *= (1.f / 64.f);
    float d = v - mu;
    float va = d * d;
#pragma unroll
    for (int o = 32; o; o >>= 1) va += __shfl_xor(va, o);
    va *= (1.f / 64.f);
    float xn = d * rsqrtf(va + 1e-6f) * g[lane] + bta[lane];
    Kd[(((size_t)b * 16 + nh) * 256 + s2) * 64 + lane] = (__bf16)xn;
  } else {
    VT[(((size_t)b * 16 + nh) * 64 + lane) * 256 + s2] = (__bf16)v;
  }
}

// ---------------- q epilogue: LN + 2D-RoPE + *SCALE -> Q (b,nh,s1,d) ------
__global__ __launch_bounds__(256) void q_epilogue(const __bf16* __restrict__ qraw,
                                                  const float* __restrict__ g,
                                                  const float* __restrict__ bta,
                                                  __bf16* __restrict__ Q) {
  const int lane = threadIdx.x & 63;
  const int vec = blockIdx.x * 4 + (threadIdx.x >> 6);  // 32768 rows * 16 heads
  const int nh = vec & 15;
  const int row = vec >> 4;            // b*4096 + s1
  float v = (float)qraw[(size_t)row * 1024 + nh * 64 + lane];
  float mu = v;
#pragma unroll
  for (int o = 32; o; o >>= 1) mu += __shfl_xor(mu, o);
  mu *= (1.f / 64.f);
  float d = v - mu;
  float va = d * d;
#pragma unroll
  for (int o = 32; o; o >>= 1) va += __shfl_xor(va, o);
  va *= (1.f / 64.f);
  float xn = d * rsqrtf(va + 1e-6f) * g[lane] + bta[lane];
  // 2D RoPE: lane d -> pair p=d>>1, t=d>>2, (p&1) selects w-axis, else h-axis
  const int s1 = row & 4095;
  const int hh = s1 >> 6, wpix = s1 & 63;
  const int t = lane >> 2;
  const int usew = (lane >> 1) & 1;
  // inv = 10000^(-t/16) = exp(-t * ln(10000)/16); hw v_exp path
  float inv = __expf(-(float)t * 0.5756462732485114f);
  float ang = (usew ? (float)wpix : (float)hh) * inv;
  float cc = __cosf(ang), ssn = __sinf(ang);   // hw v_cos/v_sin
  float partner = __shfl_xor(xn, 1);
  float rot = xn * cc + partner * ssn * ((lane & 1) ? 1.f : -1.f);
  rot *= 0.125f;  // SCALE folded into Q
  const int b = row >> 12;
  Q[(((size_t)b * 16 + nh) * 4096 + (size_t)s1) * 64 + lane] = (__bf16)rot;
}

// ---------------- fused attention: per (b,nh, 64-row q tile) --------------
// S^T = K*Q^T (MFMA, A=K from swizzled LDS, B=Q from global), softmax with
// lane-local kv values, P packed (8B writes) into sK region (swizzled),
// O = P*V with V staged in swizzled LDS.
// XOR swizzle: 16B chunk h of row r stored at h ^ (r&7) -> all wave LDS ops
// hit the 8-accesses/bank floor.
__global__ __launch_bounds__(256) void attn_kernel(const __bf16* __restrict__ Q,
                                                   const __bf16* __restrict__ Kd,
                                                   const __bf16* __restrict__ VT,
                                                   __bf16* __restrict__ O) {
  __shared__ __align__(16) __bf16 sK[256 * 64];   // K tile, rows 128B/8 chunks; reused as P (64 rows x 512B)
  __shared__ __align__(16) __bf16 sV[64 * 256];   // V^T tile, rows 512B/32 chunks
  const int tid = threadIdx.x, lane = tid & 63, w = tid >> 6;
  const int l15 = lane & 15, q4 = lane >> 4;
  const int s7 = l15 & 7;               // swizzle key for this lane's frag rows
  const int bh = blockIdx.y;            // b*16 + nh
  const int m0 = blockIdx.x * 64;       // q-row tile base
  const __bf16* Kg = Kd + (size_t)bh * 256 * 64;
  const __bf16* Vg = VT + (size_t)bh * 64 * 256;
  const __bf16* Qg = Q + ((size_t)bh * 4096 + m0) * 64;
  // stage K (rows of 64 bf16 = 8 chunks) and V^T (rows of 256 bf16 = 32 chunks)
#pragma unroll
  for (int it = 0; it < 8; ++it) {
    int c = it * 256 + tid;
    int kr = c >> 3, kh = c & 7;
    *(uint4*)(sK + kr * 64 + ((kh ^ (kr & 7)) * 8)) = *(const uint4*)(Kg + c * 8);
    int vr = c >> 5, vh = c & 31;
    *(uint4*)(sV + vr * 256 + ((vh ^ (vr & 7)) * 8)) = *(const uint4*)(Vg + c * 8);
  }
  // Q B-frags for this wave's 16 q-rows (n = l15)
  bf16x8 qf0 = *(const bf16x8*)(Qg + (w * 16 + l15) * 64 + q4 * 8);
  bf16x8 qf1 = *(const bf16x8*)(Qg + (w * 16 + l15) * 64 + 32 + q4 * 8);
  __syncthreads();
  // S^T tiles: m = kv (16 tiles), n = q (this wave's 16 rows)
  f32x4 sacc[16] = {};
#pragma unroll
  for (int mt = 0; mt < 16; ++mt) {
    bf16x8 a0 = *(const bf16x8*)(sK + (mt * 16 + l15) * 64 + ((q4 ^ s7) * 8));
    bf16x8 a1 = *(const bf16x8*)(sK + (mt * 16 + l15) * 64 + (((4 + q4) ^ s7) * 8));
    sacc[mt] = __builtin_amdgcn_mfma_f32_16x16x32_bf16(a0, qf0, sacc[mt], 0, 0, 0);
    sacc[mt] = __builtin_amdgcn_mfma_f32_16x16x32_bf16(a1, qf1, sacc[mt], 0, 0, 0);
  }
  __syncthreads();  // all waves done reading K before P overwrites sK
  // softmax over kv for q-row = w*16+l15; lane holds 64 kv values, the 4
  // lanes sharing l15 (xor 16/32) complete the 256-wide row.
  float mx = -1e30f;
#pragma unroll
  for (int mt = 0; mt < 16; ++mt)
#pragma unroll
    for (int r = 0; r < 4; ++r) mx = fmaxf(mx, sacc[mt][r]);
  mx = fmaxf(mx, __shfl_xor(mx, 16));
  mx = fmaxf(mx, __shfl_xor(mx, 32));
  float l = 0.f;
#pragma unroll
  for (int mt = 0; mt < 16; ++mt)
#pragma unroll
    for (int r = 0; r < 4; ++r) {
      float p = __expf(sacc[mt][r] - mx);
      sacc[mt][r] = p;
      l += p;
    }
  l += __shfl_xor(l, 16);
  l += __shfl_xor(l, 32);
  const float linv = 1.f / l;
  // write P (1/l folded): row q = w*16+l15, kv = mt*16 + q4*4 + {0..3} -> 8B packed
#pragma unroll
  for (int mt = 0; mt < 16; ++mt) {
    bf16x4 pk;
    pk.x = (__bf16)(sacc[mt][0] * linv);
    pk.y = (__bf16)(sacc[mt][1] * linv);
    pk.z = (__bf16)(sacc[mt][2] * linv);
    pk.w = (__bf16)(sacc[mt][3] * linv);
    int chunk = mt * 2 + (q4 >> 1);
    *(bf16x4*)(sK + (w * 16 + l15) * 256 + ((chunk ^ s7) * 8) + (q4 & 1) * 4) = pk;
  }
  // PV: A = P (own wave's rows only -> no barrier), B = V^T from sV
  f32x4 oacc[4] = {};
#pragma unroll
  for (int ks = 0; ks < 8; ++ks) {
    int phys = ((ks * 4 + q4) ^ s7) * 8;
    bf16x8 a = *(const bf16x8*)(sK + (w * 16 + l15) * 256 + phys);
#pragma unroll
    for (int j = 0; j < 4; ++j) {
      bf16x8 b = *(const bf16x8*)(sV + (j * 16 + l15) * 256 + phys);
      oacc[j] = __builtin_amdgcn_mfma_f32_16x16x32_bf16(a, b, oacc[j], 0, 0, 0);
    }
  }
  const int b = bh >> 4, nh = bh & 15;
#pragma unroll
  for (int j = 0; j < 4; ++j)
#pragma unroll
    for (int r = 0; r < 4; ++r) {
      size_t off = ((size_t)b * 4096 + m0 + w * 16 + q4 * 4 + r) * 1024
                 + nh * 64 + j * 16 + l15;
      O[off] = (__bf16)oacc[j][r];
    }
}

extern "C" void kernel_launch(void* const* d_in, const int* in_sizes, int n_in,
                              void* d_out, int out_size, void* d_ws, size_t ws_size,
                              hipStream_t stream) {
  const float* x    = (const float*)d_in[0];
  const float* y    = (const float*)d_in[1];
  const float* wq   = (const float*)d_in[2];
  const float* bq   = (const float*)d_in[3];
  const float* wkv  = (const float*)d_in[4];
  const float* bkv  = (const float*)d_in[5];
  const float* wo   = (const float*)d_in[6];
  const float* bo   = (const float*)d_in[7];
  const float* qng  = (const float*)d_in[8];
  const float* qnb  = (const float*)d_in[9];
  const float* kng  = (const float*)d_in[10];
  const float* knb  = (const float*)d_in[11];
  float* out = (float*)d_out;

  char* ws = (char*)d_ws;
  size_t off = 0;
  auto take = [&](size_t bytes) { char* p = ws + off; off += (bytes + 255) & ~(size_t)255; return p; };
  __bf16* xb   = (__bf16*)take((size_t)32768 * 1024 * 2);  // x bf16; later aliased as attn_out
  char*  reg1  = take((size_t)32768 * 1024 * 2);           // kv_f32 (head 16.8MB), then q_raw
  __bf16* Qb   = (__bf16*)take((size_t)32768 * 1024 * 2);  // final Q (b,nh,s1,d)
  __bf16* yb   = (__bf16*)take((size_t)2048 * 2048 * 2);
  __bf16* wqb  = (__bf16*)take((size_t)1024 * 1024 * 2);
  __bf16* wkvb = (__bf16*)take((size_t)2048 * 2048 * 2);
  __bf16* wob  = (__bf16*)take((size_t)1024 * 1024 * 2);
  __bf16* Kb   = (__bf16*)take((size_t)128 * 256 * 64 * 2);
  __bf16* VTb  = (__bf16*)take((size_t)128 * 64 * 256 * 2);
  float*  kvf  = (float*)reg1;    // live: kv GEMM -> kv_epilogue
  __bf16* qraw = (__bf16*)reg1;   // live: q GEMM -> q_epilogue (after kvf dead)
  __bf16* aout = xb;              // live: attn -> out GEMM (after xb dead)

  // f32 -> bf16 conversions
  cvt_bf16<<<32768, 256, 0, stream>>>(x,   xb,   8388608);
  cvt_bf16<<<4096,  256, 0, stream>>>(y,   yb,   1048576);
  cvt_bf16<<<1024,  256, 0, stream>>>(wq,  wqb,  262144);
  cvt_bf16<<<4096,  256, 0, stream>>>(wkv, wkvb, 1048576);
  cvt_bf16<<<1024,  256, 0, stream>>>(wo,  wob,  262144);

  // kv = y @ wkv^T + bkv  (f32 out), then LN(k)->K, v->V^T
  gemm_bt<false><<<dim3(16, 16), 256, 0, stream>>>(yb, wkvb, bkv, kvf, 2048, 2048, 2048);
  kv_epilogue<<<16384, 256, 0, stream>>>(kvf, kng, knb, Kb, VTb);

  // q_raw = x @ wq^T + bq (bf16 out), then LN + RoPE + scale -> Q
  gemm_bt<true><<<dim3(256, 8), 256, 0, stream>>>(xb, wqb, bq, qraw, 32768, 1024, 1024);
  q_epilogue<<<131072, 256, 0, stream>>>(qraw, qng, qnb, Qb);

  // fused attention -> aout (b,s1,nh*hd) bf16
  attn_kernel<<<dim3(64, 128), 256, 0, stream>>>(Qb, Kb, VTb, aout);

  // out = aout @ wo^T + bo (f32 out)
  gemm_bt<false><<<dim3(256, 8), 256, 0, stream>>>(aout, wob, bo, out, 32768, 1024, 1024);
}